// Round 1
// baseline (132.929 us; speedup 1.0000x reference)
//
#include <hip/hip_runtime.h>
#include <math.h>
#include <float.h>

// GLVQ: N=8192 rows, D=256 dims, P=128 prototypes, output = scalar mean.
#define N_ROWS   8192
#define DIM      256
#define NPROTO   128
#define D4       (DIM / 4)      // 64 float4 chunks per row
#define ROWS_PB  16             // rows per block
#define NBLK     (N_ROWS / ROWS_PB)  // 512 blocks -> ~2 blocks/CU

// Kernel 1: p_sq[p] = ||proto_p||^2 into ws[0..127]; zero the output scalar.
__global__ __launch_bounds__(128) void glvq_psq_kernel(
    const float* __restrict__ proto, float* __restrict__ psq,
    float* __restrict__ out) {
  int p = threadIdx.x;  // 128 threads, one prototype row each
  const float4* pr = (const float4*)proto + p * D4;
  float s = 0.f;
#pragma unroll 8
  for (int j = 0; j < D4; ++j) {
    float4 v = pr[j];
    s += v.x * v.x + v.y * v.y + v.z * v.z + v.w * v.w;
  }
  psq[p] = s;
  if (p == 0) out[0] = 0.f;  // visible to next kernel via stream order
}

// Kernel 2: main GLVQ. Block = 256 threads, 16 rows.
// Thread t: pg = t&31 -> prototypes pg*4..pg*4+3 ; rg = t>>5 -> rows rg*2, rg*2+1.
// The 32 threads sharing a row pair are contiguous lanes (half-wave) -> shfl_xor reduce.
__global__ __launch_bounds__(256) void glvq_main_kernel(
    const float* __restrict__ x, const int* __restrict__ y,
    const float* __restrict__ proto, const float* __restrict__ psq,
    float* __restrict__ out) {
  __shared__ float xsq_part[ROWS_PB][17];  // +1 pad
  __shared__ float xsq[ROWS_PB];
  __shared__ float bsum[8];

  const int t = threadIdx.x;
  const int row0 = blockIdx.x * ROWS_PB;
  const float4* x4 = (const float4*)x;
  const float4* p4 = (const float4*)proto;

  // ---- x_sq prepass: 16 threads per row, coalesced float4 reads ----
  {
    int r = t >> 4;      // 0..15
    int ci = t & 15;     // 0..15
    const float4* xr = x4 + (row0 + r) * D4;
    float s = 0.f;
#pragma unroll
    for (int j = 0; j < 4; ++j) {
      float4 v = xr[ci + 16 * j];  // consecutive threads -> consecutive float4
      s += v.x * v.x + v.y * v.y + v.z * v.z + v.w * v.w;
    }
    xsq_part[r][ci] = s;
  }
  __syncthreads();
  if (t < ROWS_PB) {
    float s = 0.f;
#pragma unroll
    for (int j = 0; j < 16; ++j) s += xsq_part[t][j];
    xsq[t] = s;
  }
  __syncthreads();

  // ---- main register-tiled dot loop: 2 rows x 4 protos per thread ----
  const int pg = t & 31;
  const int rg = t >> 5;  // 0..7
  const int ra = row0 + rg * 2;
  const int rb = ra + 1;
  const float4* xa_p = x4 + ra * D4;
  const float4* xb_p = x4 + rb * D4;
  const float4* pp0 = p4 + (pg * 4 + 0) * D4;
  const float4* pp1 = p4 + (pg * 4 + 1) * D4;
  const float4* pp2 = p4 + (pg * 4 + 2) * D4;
  const float4* pp3 = p4 + (pg * 4 + 3) * D4;

  float acc_a0 = 0.f, acc_a1 = 0.f, acc_a2 = 0.f, acc_a3 = 0.f;
  float acc_b0 = 0.f, acc_b1 = 0.f, acc_b2 = 0.f, acc_b3 = 0.f;

#pragma unroll 4
  for (int d4 = 0; d4 < D4; ++d4) {
    float4 xa = xa_p[d4];
    float4 xb = xb_p[d4];
    float4 v0 = pp0[d4];
    float4 v1 = pp1[d4];
    float4 v2 = pp2[d4];
    float4 v3 = pp3[d4];
    acc_a0 += xa.x * v0.x + xa.y * v0.y + xa.z * v0.z + xa.w * v0.w;
    acc_a1 += xa.x * v1.x + xa.y * v1.y + xa.z * v1.z + xa.w * v1.w;
    acc_a2 += xa.x * v2.x + xa.y * v2.y + xa.z * v2.z + xa.w * v2.w;
    acc_a3 += xa.x * v3.x + xa.y * v3.y + xa.z * v3.z + xa.w * v3.w;
    acc_b0 += xb.x * v0.x + xb.y * v0.y + xb.z * v0.z + xb.w * v0.w;
    acc_b1 += xb.x * v1.x + xb.y * v1.y + xb.z * v1.z + xb.w * v1.w;
    acc_b2 += xb.x * v2.x + xb.y * v2.y + xb.z * v2.z + xb.w * v2.w;
    acc_b3 += xb.x * v3.x + xb.y * v3.y + xb.z * v3.z + xb.w * v3.w;
  }

  // ---- epilogue: dist = xsq - 2*dot + psq; d1 (p==y), d2 (min over others) ----
  const int ya = y[ra];
  const int yb = y[rb];
  const float xsa = xsq[rg * 2];
  const float xsb = xsq[rg * 2 + 1];

  float d1a = FLT_MAX, d2a = FLT_MAX, d1b = FLT_MAX, d2b = FLT_MAX;
  float accs_a[4] = {acc_a0, acc_a1, acc_a2, acc_a3};
  float accs_b[4] = {acc_b0, acc_b1, acc_b2, acc_b3};
#pragma unroll
  for (int i = 0; i < 4; ++i) {
    int p = pg * 4 + i;
    float pq = psq[p];
    float da = xsa + pq - 2.f * accs_a[i];
    float db = xsb + pq - 2.f * accs_b[i];
    if (p == ya) d1a = da; else d2a = fminf(d2a, da);
    if (p == yb) d1b = db; else d2b = fminf(d2b, db);
  }

  // 32-lane butterfly min-reduce (threads sharing a row pair are one half-wave)
#pragma unroll
  for (int m = 1; m <= 16; m <<= 1) {
    d1a = fminf(d1a, __shfl_xor(d1a, m));
    d2a = fminf(d2a, __shfl_xor(d2a, m));
    d1b = fminf(d1b, __shfl_xor(d1b, m));
    d2b = fminf(d2b, __shfl_xor(d2b, m));
  }

  if (pg == 0) {
    float mua = (d1a - d2a) / (d1a + d2a);
    float mub = (d1b - d2b) / (d1b + d2b);
    // sigmoid(-mu) = 1/(1+exp(mu)); mu in (-1,1) so no range issues
    float s = 1.f / (1.f + __expf(mua)) + 1.f / (1.f + __expf(mub));
    bsum[rg] = s;
  }
  __syncthreads();
  if (t == 0) {
    float s = 0.f;
#pragma unroll
    for (int j = 0; j < 8; ++j) s += bsum[j];
    atomicAdd(out, s * (1.f / (float)N_ROWS));
  }
}

extern "C" void kernel_launch(void* const* d_in, const int* in_sizes, int n_in,
                              void* d_out, int out_size, void* d_ws, size_t ws_size,
                              hipStream_t stream) {
  const float* x = (const float*)d_in[0];       // [8192, 256] fp32
  const int* y = (const int*)d_in[1];           // [8192] int32
  const float* proto = (const float*)d_in[2];   // [128, 256] fp32
  float* out = (float*)d_out;                   // scalar fp32
  float* psq = (float*)d_ws;                    // 128 floats of scratch

  glvq_psq_kernel<<<1, NPROTO, 0, stream>>>(proto, psq, out);
  glvq_main_kernel<<<NBLK, 256, 0, stream>>>(x, y, proto, psq, out);
}

// Round 2
// 75.935 us; speedup vs baseline: 1.7505x; 1.7505x over previous
//
#include <hip/hip_runtime.h>
#include <math.h>

// GLVQ via bf16 MFMA: C = X[8192x256] . P^T[256x128], fused d1/d2/sigmoid/mean.
#define N_ROWS  8192
#define DIM     256
#define NPROTO  128
#define ROWS_PB 16
#define NBLK    (N_ROWS / ROWS_PB)  // 512 blocks -> 2 blocks/CU
#define PSTR    264                 // LDS row stride in bf16 elems (256 + 8 pad -> bank-balanced)

typedef float f32x4 __attribute__((ext_vector_type(4)));
typedef short s16x8 __attribute__((ext_vector_type(8)));

__device__ __forceinline__ unsigned short f2bf(float f) {
  // fp32 -> bf16 round-to-nearest-even (inputs are finite gaussians, no NaN/inf)
  unsigned int u = __float_as_uint(f);
  u += 0x7fffu + ((u >> 16) & 1u);
  return (unsigned short)(u >> 16);
}

__global__ __launch_bounds__(256, 2) void glvq_kernel(
    const float* __restrict__ x, const int* __restrict__ y,
    const float* __restrict__ proto, float* __restrict__ out) {
  __shared__ unsigned short pT[NPROTO * PSTR];   // 67584 B, bf16 protos, padded rows
  __shared__ unsigned short xT[ROWS_PB * PSTR];  // 8448 B,  bf16 x-tile
  __shared__ float psq[NPROTO];
  __shared__ float xsq[ROWS_PB];
  __shared__ int   ylds[ROWS_PB];
  __shared__ float red1[4 * ROWS_PB];
  __shared__ float red2[4 * ROWS_PB];

  const int t = threadIdx.x;
  const int r0 = blockIdx.x * ROWS_PB;

  // ---- phase 1a: protos fp32 -> bf16 LDS (coalesced), fold exact-fp32 psq ----
  {
    const float4* p4 = (const float4*)proto;
#pragma unroll
    for (int j = 0; j < 16; ++j) {
      int c = j * 256 + t;          // 8-float chunk index, 4096 total
      float4 a = p4[c * 2];
      float4 b = p4[c * 2 + 1];
      int p = c >> 5;               // 32 chunks per proto row
      int ci = c & 31;
      union { s16x8 v; unsigned short u[8]; } pk;
      pk.u[0] = f2bf(a.x); pk.u[1] = f2bf(a.y); pk.u[2] = f2bf(a.z); pk.u[3] = f2bf(a.w);
      pk.u[4] = f2bf(b.x); pk.u[5] = f2bf(b.y); pk.u[6] = f2bf(b.z); pk.u[7] = f2bf(b.w);
      *(s16x8*)&pT[p * PSTR + ci * 8] = pk.v;  // 16B aligned (528*p + 16*ci)
      float s = a.x * a.x + a.y * a.y + a.z * a.z + a.w * a.w +
                b.x * b.x + b.y * b.y + b.z * b.z + b.w * b.w;
      // 32 consecutive threads share one proto row -> shfl reduce
#pragma unroll
      for (int m = 1; m <= 16; m <<= 1) s += __shfl_xor(s, m);
      if ((t & 31) == 0) psq[j * 8 + (t >> 5)] = s;
    }
  }

  // ---- phase 1b: x-tile fp32 -> bf16 LDS, exact-fp32 xsq; y -> LDS ----
  {
    const float4* x4 = (const float4*)x;
    int r = t >> 4, ci = t & 15;
    const float4* xr = x4 + (size_t)(r0 + r) * (DIM / 4);
    float s = 0.f;
#pragma unroll
    for (int j = 0; j < 4; ++j) {
      float4 v = xr[ci + 16 * j];
      s += v.x * v.x + v.y * v.y + v.z * v.z + v.w * v.w;
      uint2 w2;
      w2.x = (unsigned)f2bf(v.x) | ((unsigned)f2bf(v.y) << 16);
      w2.y = (unsigned)f2bf(v.z) | ((unsigned)f2bf(v.w) << 16);
      *(uint2*)&xT[r * PSTR + (ci + 16 * j) * 4] = w2;  // 8B aligned
    }
#pragma unroll
    for (int m = 1; m <= 8; m <<= 1) s += __shfl_xor(s, m);
    if (ci == 0) xsq[r] = s;
    if (t < ROWS_PB) ylds[t] = y[r0 + t];
  }
  __syncthreads();

  // ---- phase 2: MFMA. wave w -> protos [w*32, w*32+32), all 16 rows, K=256 ----
  const int l = t & 63;
  const int w = t >> 6;
  const int mq = l >> 4;   // quad 0..3
  const int mc = l & 15;   // A row / B col within tile
  f32x4 acc0 = {0.f, 0.f, 0.f, 0.f};
  f32x4 acc1 = {0.f, 0.f, 0.f, 0.f};
  const unsigned short* aptr = &xT[mc * PSTR + mq * 8];
  const unsigned short* b0p  = &pT[(w * 32 + mc) * PSTR + mq * 8];
  const unsigned short* b1p  = b0p + 16 * PSTR;
#pragma unroll
  for (int ks = 0; ks < 8; ++ks) {
    s16x8 af  = *(const s16x8*)(aptr + ks * 32);
    s16x8 bf0 = *(const s16x8*)(b0p + ks * 32);
    s16x8 bf1 = *(const s16x8*)(b1p + ks * 32);
    acc0 = __builtin_amdgcn_mfma_f32_16x16x32_bf16(af, bf0, acc0, 0, 0, 0);
    acc1 = __builtin_amdgcn_mfma_f32_16x16x32_bf16(af, bf1, acc1, 0, 0, 0);
  }

  // ---- phase 3: dists + per-row d1/d2 within wave ----
  // C/D layout (verified m89): col = lane&15 (proto), row = (lane>>4)*4 + reg (x-row)
  const int p0i = w * 32 + mc;
  const int p1i = p0i + 16;
  const float pq0 = psq[p0i];
  const float pq1 = psq[p1i];
  float r1[4], r2[4];
#pragma unroll
  for (int reg = 0; reg < 4; ++reg) {
    int m = mq * 4 + reg;
    float xs = xsq[m];
    int ym = ylds[m];
    float d0 = xs + pq0 - 2.f * acc0[reg];
    float d1_ = xs + pq1 - 2.f * acc1[reg];
    float dd1 = 1e30f, dd2 = 1e30f;
    if (p0i == ym) dd1 = d0; else dd2 = d0;
    if (p1i == ym) dd1 = fminf(dd1, d1_); else dd2 = fminf(dd2, d1_);
    r1[reg] = dd1;
    r2[reg] = dd2;
  }
#pragma unroll
  for (int m = 1; m <= 8; m <<= 1) {
#pragma unroll
    for (int reg = 0; reg < 4; ++reg) {
      r1[reg] = fminf(r1[reg], __shfl_xor(r1[reg], m));
      r2[reg] = fminf(r2[reg], __shfl_xor(r2[reg], m));
    }
  }
  if (mc == 0) {
#pragma unroll
    for (int reg = 0; reg < 4; ++reg) {
      red1[w * ROWS_PB + mq * 4 + reg] = r1[reg];
      red2[w * ROWS_PB + mq * 4 + reg] = r2[reg];
    }
  }
  __syncthreads();

  // ---- phase 4: combine 4 waves, sigmoid, block sum, one atomic ----
  if (t < ROWS_PB) {
    float d1 = 1e30f, d2 = 1e30f;
#pragma unroll
    for (int wv = 0; wv < 4; ++wv) {
      d1 = fminf(d1, red1[wv * ROWS_PB + t]);
      d2 = fminf(d2, red2[wv * ROWS_PB + t]);
    }
    float mu = (d1 - d2) / (d1 + d2);
    float s = 1.f / (1.f + __expf(mu));  // sigmoid(-mu)
#pragma unroll
    for (int m = 1; m <= 8; m <<= 1) s += __shfl_xor(s, m);  // lanes 0..15 only
    if (t == 0) atomicAdd(out, s * (1.f / (float)N_ROWS));
  }
}

extern "C" void kernel_launch(void* const* d_in, const int* in_sizes, int n_in,
                              void* d_out, int out_size, void* d_ws, size_t ws_size,
                              hipStream_t stream) {
  const float* x = (const float*)d_in[0];       // [8192, 256] fp32
  const int* y = (const int*)d_in[1];           // [8192] int32
  const float* proto = (const float*)d_in[2];   // [128, 256] fp32
  float* out = (float*)d_out;                   // scalar fp32

  hipMemsetAsync(out, 0, sizeof(float), stream);  // graph-capturable memset node
  glvq_kernel<<<NBLK, 256, 0, stream>>>(x, y, proto, out);
}

// Round 3
// 70.781 us; speedup vs baseline: 1.8780x; 1.0728x over previous
//
#include <hip/hip_runtime.h>
#include <math.h>

// GLVQ via bf16 MFMA, 2-kernel: prep (proto->bf16 + psq + zero out), main (fused GEMM+epilogue).
#define N_ROWS  8192
#define DIM     256
#define NPROTO  128
#define ROWS_PB 16
#define NBLK    (N_ROWS / ROWS_PB)  // 512 blocks -> 2 blocks/CU
#define PSTR    264                 // LDS row stride in bf16 elems (256+8 pad -> 2-way (free) b128 conflicts)

typedef float f32x4 __attribute__((ext_vector_type(4)));
typedef short s16x8 __attribute__((ext_vector_type(8)));

__device__ __forceinline__ unsigned short f2bf(float f) {
  // fp32 -> bf16 RNE (finite inputs)
  unsigned int u = __float_as_uint(f);
  u += 0x7fffu + ((u >> 16) & 1u);
  return (unsigned short)(u >> 16);
}

// ---- prep: proto fp32 -> bf16 into ws, exact psq[128] into ws, zero out ----
// 32 blocks x 256 threads; 1 float4 per thread; one wave covers one proto row.
__global__ __launch_bounds__(256) void glvq_prep_kernel(
    const float* __restrict__ proto, unsigned short* __restrict__ pbf,
    float* __restrict__ psq, float* __restrict__ out) {
  const int tid = blockIdx.x * 256 + threadIdx.x;  // 0..8191 = float4 index
  float4 v = ((const float4*)proto)[tid];
  uint2 w2;
  w2.x = (unsigned)f2bf(v.x) | ((unsigned)f2bf(v.y) << 16);
  w2.y = (unsigned)f2bf(v.z) | ((unsigned)f2bf(v.w) << 16);
  *(uint2*)&pbf[tid * 4] = w2;  // coalesced 8B stores
  float s = v.x * v.x + v.y * v.y + v.z * v.z + v.w * v.w;
#pragma unroll
  for (int m = 1; m <= 32; m <<= 1) s += __shfl_xor(s, m);  // 64-lane reduce
  if ((threadIdx.x & 63) == 0) psq[tid >> 6] = s;           // row = tid/64
  if (tid == 0) out[0] = 0.f;
}

// ---- main: per block 16 rows; stage bf16 protos (copy) + x (convert) to LDS; MFMA; epilogue ----
__global__ __launch_bounds__(256, 2) void glvq_kernel(
    const float* __restrict__ x, const int* __restrict__ y,
    const unsigned short* __restrict__ pbf, const float* __restrict__ psq_g,
    float* __restrict__ out) {
  __shared__ unsigned short pT[NPROTO * PSTR];   // 67584 B
  __shared__ unsigned short xT[ROWS_PB * PSTR];  // 8448 B
  __shared__ float psq[NPROTO];
  __shared__ float xsq[ROWS_PB];
  __shared__ int   ylds[ROWS_PB];
  __shared__ float red1[4 * ROWS_PB];
  __shared__ float red2[4 * ROWS_PB];

  const int t = threadIdx.x;
  const int r0 = blockIdx.x * ROWS_PB;

  // phase 1a: bf16 protos global -> padded LDS (pure copy, coalesced 16B loads)
  {
    const uint4* src = (const uint4*)pbf;  // 16B = 8 bf16 chunks, 4096 total
#pragma unroll
    for (int j = 0; j < 16; ++j) {
      int c = j * 256 + t;
      uint4 v = src[c];
      int p = c >> 5;   // 32 chunks per proto row
      int ci = c & 31;
      *(uint4*)&pT[p * PSTR + ci * 8] = v;  // 16B-aligned (528B row stride)
    }
    if (t < NPROTO) psq[t] = psq_g[t];
  }

  // phase 1b: x fp32 -> bf16 LDS + exact xsq; y -> LDS
  {
    const float4* x4 = (const float4*)x;
    int r = t >> 4, ci = t & 15;
    const float4* xr = x4 + (size_t)(r0 + r) * (DIM / 4);
    float s = 0.f;
#pragma unroll
    for (int j = 0; j < 4; ++j) {
      float4 v = xr[ci + 16 * j];
      s += v.x * v.x + v.y * v.y + v.z * v.z + v.w * v.w;
      uint2 w2;
      w2.x = (unsigned)f2bf(v.x) | ((unsigned)f2bf(v.y) << 16);
      w2.y = (unsigned)f2bf(v.z) | ((unsigned)f2bf(v.w) << 16);
      *(uint2*)&xT[r * PSTR + (ci + 16 * j) * 4] = w2;
    }
#pragma unroll
    for (int m = 1; m <= 8; m <<= 1) s += __shfl_xor(s, m);
    if (ci == 0) xsq[r] = s;
    if (t < ROWS_PB) ylds[t] = y[r0 + t];
  }
  __syncthreads();

  // phase 2: wave w -> protos [w*32, w*32+32), 16 rows, K=256 (8 MFMA steps x 2 tiles)
  const int l = t & 63;
  const int w = t >> 6;
  const int mq = l >> 4;
  const int mc = l & 15;
  f32x4 acc0 = {0.f, 0.f, 0.f, 0.f};
  f32x4 acc1 = {0.f, 0.f, 0.f, 0.f};
  const unsigned short* aptr = &xT[mc * PSTR + mq * 8];
  const unsigned short* b0p  = &pT[(w * 32 + mc) * PSTR + mq * 8];
  const unsigned short* b1p  = b0p + 16 * PSTR;
#pragma unroll
  for (int ks = 0; ks < 8; ++ks) {
    s16x8 af  = *(const s16x8*)(aptr + ks * 32);
    s16x8 bf0 = *(const s16x8*)(b0p + ks * 32);
    s16x8 bf1 = *(const s16x8*)(b1p + ks * 32);
    acc0 = __builtin_amdgcn_mfma_f32_16x16x32_bf16(af, bf0, acc0, 0, 0, 0);
    acc1 = __builtin_amdgcn_mfma_f32_16x16x32_bf16(af, bf1, acc1, 0, 0, 0);
  }

  // phase 3: dist = xsq + psq - 2*dot; d1 (p==y) / d2 (min others); 16-lane reduce
  // C/D layout (m89): col = lane&15 (proto), row = (lane>>4)*4 + reg (x-row)
  const int p0i = w * 32 + mc;
  const int p1i = p0i + 16;
  const float pq0 = psq[p0i];
  const float pq1 = psq[p1i];
  float r1[4], r2[4];
#pragma unroll
  for (int reg = 0; reg < 4; ++reg) {
    int m = mq * 4 + reg;
    float xs = xsq[m];
    int ym = ylds[m];
    float d0 = xs + pq0 - 2.f * acc0[reg];
    float d1_ = xs + pq1 - 2.f * acc1[reg];
    float dd1 = 1e30f, dd2 = 1e30f;
    if (p0i == ym) dd1 = d0; else dd2 = d0;
    if (p1i == ym) dd1 = fminf(dd1, d1_); else dd2 = fminf(dd2, d1_);
    r1[reg] = dd1;
    r2[reg] = dd2;
  }
#pragma unroll
  for (int m = 1; m <= 8; m <<= 1) {
#pragma unroll
    for (int reg = 0; reg < 4; ++reg) {
      r1[reg] = fminf(r1[reg], __shfl_xor(r1[reg], m));
      r2[reg] = fminf(r2[reg], __shfl_xor(r2[reg], m));
    }
  }
  if (mc == 0) {
#pragma unroll
    for (int reg = 0; reg < 4; ++reg) {
      red1[w * ROWS_PB + mq * 4 + reg] = r1[reg];
      red2[w * ROWS_PB + mq * 4 + reg] = r2[reg];
    }
  }
  __syncthreads();

  // phase 4: combine waves, sigmoid, block sum, one atomic
  if (t < ROWS_PB) {
    float d1 = 1e30f, d2 = 1e30f;
#pragma unroll
    for (int wv = 0; wv < 4; ++wv) {
      d1 = fminf(d1, red1[wv * ROWS_PB + t]);
      d2 = fminf(d2, red2[wv * ROWS_PB + t]);
    }
    float mu = (d1 - d2) / (d1 + d2);
    float s = 1.f / (1.f + __expf(mu));  // sigmoid(-mu)
#pragma unroll
    for (int m = 1; m <= 8; m <<= 1) s += __shfl_xor(s, m);  // lanes 0..15
    if (t == 0) atomicAdd(out, s * (1.f / (float)N_ROWS));
  }
}

extern "C" void kernel_launch(void* const* d_in, const int* in_sizes, int n_in,
                              void* d_out, int out_size, void* d_ws, size_t ws_size,
                              hipStream_t stream) {
  const float* x = (const float*)d_in[0];       // [8192, 256] fp32
  const int* y = (const int*)d_in[1];           // [8192] int32
  const float* proto = (const float*)d_in[2];   // [128, 256] fp32
  float* out = (float*)d_out;                   // scalar fp32

  unsigned short* pbf = (unsigned short*)d_ws;               // 64 KB bf16 protos
  float* psq = (float*)((char*)d_ws + NPROTO * DIM * 2);     // 512 B psq

  glvq_prep_kernel<<<32, 256, 0, stream>>>(proto, pbf, psq, out);
  glvq_kernel<<<NBLK, 256, 0, stream>>>(x, y, pbf, psq, out);
}